// Round 1
// 416.270 us; speedup vs baseline: 1.0762x; 1.0762x over previous
//
#include <hip/hip_runtime.h>
#include <stdint.h>

// Problem constants
#define BB   8
#define CC   64
#define HH   256
#define WW   256
#define HWSZ (HH*WW)              // 65536
#define CHW  (CC*HH*WW)           // 4194304
#define GROUPELEMS (8*HWSZ)       // 524288 (channels-per-group=8)
#define EPSV 1e-5f

// ws layout (bytes)
#define WS_PART_OFF  0            // 512 x float2   (4 KiB)
#define WS_AFF_OFF   4096         // 512 x float2   (4 KiB)
#define WS_WFRAG_OFF 8192         // 4096 x uint32  (16 KiB)  A-fragment packed weights

typedef __attribute__((ext_vector_type(8))) short bf16x8;
typedef __attribute__((ext_vector_type(4))) float f32x4;
union U32x4 { uint32_t u[4]; uint4 q; bf16x8 v; };

__device__ __forceinline__ uint32_t f32_to_bf16_bits(float f) {
    uint32_t u = __float_as_uint(f);
    u += 0x7fffu + ((u >> 16) & 1u);   // RNE
    return u >> 16;
}

// ---------------- K0: pack fp32 weights into MFMA A-fragment layout --------
// M = 128 (gate rows 0..63, upd rows 64..127), K = 64. 16 frags (8 mt x 2 s),
// lane l holds A[m=16mt+(l&15)][k=32s+8(l>>4)+j], j=0..7 -> 4 dwords.
__global__ __launch_bounds__(256) void k_wfrag(
        const float* __restrict__ gw, const float* __restrict__ uw,
        uint32_t* __restrict__ wfrag) {
    int idx = blockIdx.x * 256 + threadIdx.x;     // 0..4095
    int fi = idx >> 8, rem = idx & 255;
    int l = rem >> 2, d = rem & 3;
    int mt = fi >> 1, s = fi & 1;
    int m = 16 * mt + (l & 15);
    int k = 32 * s + 8 * (l >> 4) + 2 * d;
    const float* Wr = (m < 64) ? (gw + m * 64) : (uw + (m - 64) * 64);
    wfrag[idx] = f32_to_bf16_bits(Wr[k]) | (f32_to_bf16_bits(Wr[k + 1]) << 16);
}

// ---------------- K1: per-slice partial sums for GroupNorm stats ------------
__global__ __launch_bounds__(256) void k_stats_partial(
        const float* __restrict__ x, float2* __restrict__ part) {
    int blk = blockIdx.x;
    const float4* p = (const float4*)(x + (size_t)blk * 65536);
    int t = threadIdx.x;
    float s = 0.f, s2 = 0.f;
#pragma unroll 16
    for (int i = 0; i < 64; ++i) {
        float4 v = p[t + i * 256];
        s  += v.x + v.y + v.z + v.w;
        s2 += v.x * v.x + v.y * v.y + v.z * v.z + v.w * v.w;
    }
#pragma unroll
    for (int off = 32; off; off >>= 1) {
        s  += __shfl_down(s,  off, 64);
        s2 += __shfl_down(s2, off, 64);
    }
    __shared__ float2 red[4];
    int wid = t >> 6;
    if ((t & 63) == 0) red[wid] = make_float2(s, s2);
    __syncthreads();
    if (t == 0) {
        float a = 0.f, b2 = 0.f;
#pragma unroll
        for (int i = 0; i < 4; ++i) { a += red[i].x; b2 += red[i].y; }
        part[blk] = make_float2(a, b2);
    }
}

// ---------------- K1b: finalize stats -> per-(b,c) affine ------------------
__global__ __launch_bounds__(512) void k_stats_final(
        const float2* __restrict__ part,
        const float* __restrict__ gn_w, const float* __restrict__ gn_b,
        float2* __restrict__ aff) {
    __shared__ float2 st[64];
    int t = threadIdx.x;
    if (t < 64) {
        float s = 0.f, s2 = 0.f;
#pragma unroll
        for (int i = 0; i < 8; ++i) { float2 p = part[t * 8 + i]; s += p.x; s2 += p.y; }
        float inv  = 1.0f / (float)GROUPELEMS;
        float mu   = s * inv;
        float var  = s2 * inv - mu * mu;
        st[t] = make_float2(mu, rsqrtf(var + EPSV));
    }
    __syncthreads();
    int b = t >> 6, c = t & 63, g = c >> 3;
    float2 mr = st[b * 8 + g];
    float a  = mr.y * gn_w[c];
    aff[t] = make_float2(a, gn_b[c] - mr.x * a);
}

// ---------------- K2: MFMA row kernel — norm, convs, sigmoid, W-scan -------
// grid = B*H = 2048 blocks x 256. Two halves of 128 px per row.
// LDS: single overlaid buffer gvhn[128][65] (33280 B) + affs/bgs/bus (1024 B)
//      = 34304 B  -> 4 blocks/CU LDS-wise.
// __launch_bounds__(256,4) forces VGPR<=128 -> 4 waves/SIMD (4 blocks/CU).
// Overlay safety: per row px, lane q reads hn dwords {4q..4q+3,16+4q..16+4q+3}
// and the SAME lane is the only writer of those dwords in the epilogue
// (c = 16*mt+4*q+r, mt=0,1), so read-before-write holds in program order.
__global__ __launch_bounds__(256, 4) void k_row(
        const float* __restrict__ x,
        const uint32_t* __restrict__ wfrag,
        const float* __restrict__ gate_b, const float* __restrict__ upd_b,
        const float2* __restrict__ aff,
        uint32_t* __restrict__ pair) {
    __shared__ uint32_t gvhn[128 * 65];   // [px][dword], stride 65
    __shared__ float2 affs[64];
    __shared__ __align__(16) float bgs[64];
    __shared__ __align__(16) float bus[64];

    const int t = threadIdx.x;
    const int w = t >> 6, l = t & 63, q = l >> 4, r16 = l & 15;
    const int row = blockIdx.x;
    const int b = row >> 8, y = row & 255;
    const size_t rowoff = (size_t)b * CHW + (size_t)y * WW;

    if (t < 64) { affs[t] = aff[b * 64 + t]; bgs[t] = gate_b[t]; bus[t] = upd_b[t]; }

    // A fragments: 16 coalesced dwordx4 loads (64 VGPRs, live whole kernel)
    bf16x8 A[8][2];
#pragma unroll
    for (int mt = 0; mt < 8; ++mt)
#pragma unroll
        for (int s = 0; s < 2; ++s) {
            U32x4 u;
            u.q = *(const uint4*)(wfrag + (((mt << 1) | s) * 64 + l) * 4);
            A[mt][s] = u.v;
        }
    __syncthreads();

    float s_carry = 0.f;
    for (int tau = 0; tau < 2; ++tau) {
        const int x0 = tau << 7;
        // ---- stage normalized bf16 tile: 8 float4 loads, 16 b32 LDS writes -
        // lane group of 32 shares c2, consecutive p4 -> 512 B coalesced loads
#pragma unroll
        for (int i = 0; i < 4; ++i) {
            int unit = i * 256 + t;          // 0..1023
            int c2 = unit >> 5, p4 = unit & 31;
            int c = c2 << 1, px = p4 << 2;
            const float* xp = x + rowoff + (size_t)c * HWSZ + x0 + px;
            float4 v0 = *(const float4*)xp;
            float4 v1 = *(const float4*)(xp + HWSZ);
            float2 a0 = affs[c], a1 = affs[c + 1];
            uint32_t base = px * 65 + c2;
            gvhn[base]       = f32_to_bf16_bits(v0.x * a0.x + a0.y)
                             | (f32_to_bf16_bits(v1.x * a1.x + a1.y) << 16);
            gvhn[base + 65]  = f32_to_bf16_bits(v0.y * a0.x + a0.y)
                             | (f32_to_bf16_bits(v1.y * a1.x + a1.y) << 16);
            gvhn[base + 130] = f32_to_bf16_bits(v0.z * a0.x + a0.y)
                             | (f32_to_bf16_bits(v1.z * a1.x + a1.y) << 16);
            gvhn[base + 195] = f32_to_bf16_bits(v0.w * a0.x + a0.y)
                             | (f32_to_bf16_bits(v1.w * a1.x + a1.y) << 16);
        }
        __syncthreads();

        // ---- MFMA: wave w owns local px [32w, 32w+32) = 2 N-chunks of 16 ---
#pragma unroll
        for (int nc = 0; nc < 2; ++nc) {
            int n_local = (w << 5) + (nc << 4) + r16;
            int based = n_local * 65 + 4 * q;
            U32x4 B0u, B1u;
#pragma unroll
            for (int d = 0; d < 4; ++d) B0u.u[d] = gvhn[based + d];        // k=8q..8q+7
#pragma unroll
            for (int d = 0; d < 4; ++d) B1u.u[d] = gvhn[based + 16 + d];   // +32
            // acc init = bias, read as aligned f32x4 broadcast from LDS
            f32x4 acc[8];
#pragma unroll
            for (int mt = 0; mt < 4; ++mt) {
                acc[mt]     = *(const f32x4*)(bgs + 16 * mt + 4 * q);
                acc[mt + 4] = *(const f32x4*)(bus + 16 * mt + 4 * q);
            }
#pragma unroll
            for (int mt = 0; mt < 8; ++mt)
                acc[mt] = __builtin_amdgcn_mfma_f32_16x16x32_bf16(A[mt][0], B0u.v, acc[mt], 0, 0, 0);
#pragma unroll
            for (int mt = 0; mt < 8; ++mt)
                acc[mt] = __builtin_amdgcn_mfma_f32_16x16x32_bf16(A[mt][1], B1u.v, acc[mt], 0, 0, 0);
            // epilogue: sigmoid + pack (g | (1-g)*u<<16) via v_perm
#pragma unroll
            for (int mt = 0; mt < 4; ++mt)
#pragma unroll
                for (int r = 0; r < 4; ++r) {
                    float ga = acc[mt][r];
                    float ua = acc[mt + 4][r];
                    float g  = 1.0f / (1.0f + __expf(-ga));
                    float vv = (1.0f - g) * ua;
                    uint32_t pk = __builtin_amdgcn_perm(__float_as_uint(vv),
                                                        __float_as_uint(g), 0x07060302u);
                    gvhn[n_local * 65 + 16 * mt + 4 * q + r] = pk;
                }
        }
        __syncthreads();

        // ---- W-scan: thread c (<64) serial over 128 px; banks 2-way -------
        if (t < 64) {
            float s = s_carry;
#pragma unroll 8
            for (int xi = 0; xi < 128; ++xi) {
                uint32_t pk = gvhn[xi * 65 + t];
                float g = __uint_as_float(pk << 16);
                float v = __uint_as_float(pk & 0xffff0000u);
                s = __builtin_fmaf(g, s, v);
                gvhn[xi * 65 + t] = __builtin_amdgcn_perm(__float_as_uint(s), pk, 0x07060100u);
            }
            s_carry = s;
        }
        __syncthreads();

        // ---- write packed (gate, hw): 8 uint4 stores, 512 B coalesced -----
#pragma unroll
        for (int i = 0; i < 8; ++i) {
            int unit = i * 256 + t;          // 0..2047
            int c = unit >> 5, p4 = unit & 31;
            int px = p4 << 2;
            uint32_t bidx = px * 65 + c;
            uint4 o;
            o.x = gvhn[bidx];
            o.y = gvhn[bidx + 65];
            o.z = gvhn[bidx + 130];
            o.w = gvhn[bidx + 195];
            *(uint4*)(pair + rowoff + (size_t)c * HWSZ + x0 + px) = o;
        }
        __syncthreads();
    }
}

// ---------------- K3: H-scan + residual, prefetched, in-place on d_out -----
__global__ __launch_bounds__(256) void k_hscan(
        uint32_t* __restrict__ io, const float* __restrict__ x) {
    int t = threadIdx.x;
    size_t base = (size_t)blockIdx.x * HWSZ + t;
    uint32_t pk[16]; float xv[16];
#pragma unroll
    for (int j = 0; j < 16; ++j) pk[j] = io[base + (size_t)j * WW];
#pragma unroll
    for (int j = 0; j < 16; ++j) xv[j] = x[base + (size_t)j * WW];
    float s = 0.f;
    for (int yt = 0; yt < 16; ++yt) {
        uint32_t npk[16]; float nxv[16];
        if (yt < 15) {                       // prefetch next 16-row group
            size_t nb = base + (size_t)(yt + 1) * 16 * WW;
#pragma unroll
            for (int j = 0; j < 16; ++j) npk[j] = io[nb + (size_t)j * WW];
#pragma unroll
            for (int j = 0; j < 16; ++j) nxv[j] = x[nb + (size_t)j * WW];
        }
        float gj[16], vj[16];                // hoist unpack out of serial chain
#pragma unroll
        for (int j = 0; j < 16; ++j) {
            float g   = __uint_as_float(pk[j] << 16);
            float hwv = __uint_as_float(pk[j] & 0xffff0000u);
            gj[j] = g; vj[j] = (1.f - g) * hwv;
        }
        float res[16];
#pragma unroll
        for (int j = 0; j < 16; ++j) { s = __builtin_fmaf(gj[j], s, vj[j]); res[j] = xv[j] + s; }
        size_t ob = base + (size_t)yt * 16 * WW;
#pragma unroll
        for (int j = 0; j < 16; ++j) io[ob + (size_t)j * WW] = __float_as_uint(res[j]);
#pragma unroll
        for (int j = 0; j < 16; ++j) { pk[j] = npk[j]; xv[j] = nxv[j]; }
    }
}

extern "C" void kernel_launch(void* const* d_in, const int* in_sizes, int n_in,
                              void* d_out, int out_size, void* d_ws, size_t ws_size,
                              hipStream_t stream) {
    const float* x      = (const float*)d_in[0];
    const float* gn_w   = (const float*)d_in[1];
    const float* gn_b   = (const float*)d_in[2];
    const float* gate_w = (const float*)d_in[3];
    const float* gate_b = (const float*)d_in[4];
    const float* upd_w  = (const float*)d_in[5];
    const float* upd_b  = (const float*)d_in[6];

    char* ws = (char*)d_ws;
    float2*   part  = (float2*)(ws + WS_PART_OFF);
    float2*   aff   = (float2*)(ws + WS_AFF_OFF);
    uint32_t* wfrag = (uint32_t*)(ws + WS_WFRAG_OFF);
    uint32_t* pair  = (uint32_t*)d_out;   // packed (gate,hw); K3 rewrites in place

    k_wfrag<<<16, 256, 0, stream>>>(gate_w, upd_w, wfrag);
    k_stats_partial<<<512, 256, 0, stream>>>(x, part);
    k_stats_final<<<1, 512, 0, stream>>>(part, gn_w, gn_b, aff);
    k_row<<<BB * HH, 256, 0, stream>>>(x, wfrag, gate_b, upd_b, aff, pair);
    k_hscan<<<BB * CC, 256, 0, stream>>>(pair, x);
}

// Round 3
// 396.724 us; speedup vs baseline: 1.1292x; 1.0493x over previous
//
#include <hip/hip_runtime.h>
#include <stdint.h>

// Problem constants
#define BB   8
#define CC   64
#define HH   256
#define WW   256
#define HWSZ (HH*WW)              // 65536
#define CHW  (CC*HH*WW)           // 4194304
#define GROUPELEMS (8*HWSZ)       // 524288 (channels-per-group=8)
#define EPSV 1e-5f

// ws layout (bytes)
#define WS_PART_OFF  0            // 512 x float2   (4 KiB)
#define WS_AFF_OFF   4096         // 512 x float2   (4 KiB)
#define WS_WFRAG_OFF 8192         // 4096 x uint32  (16 KiB)  A-fragment packed weights

typedef __attribute__((ext_vector_type(8))) short bf16x8;
typedef __attribute__((ext_vector_type(4))) float f32x4;
typedef __attribute__((ext_vector_type(4))) unsigned int u32x4;  // native vec for NT store
union U32x4 { uint32_t u[4]; uint4 q; bf16x8 v; u32x4 nv; };

__device__ __forceinline__ uint32_t f32_to_bf16_bits(float f) {
    uint32_t u = __float_as_uint(f);
    u += 0x7fffu + ((u >> 16) & 1u);   // RNE
    return u >> 16;
}

// ---------------- K1: per-slice partial sums for GroupNorm stats ------------
// Fused: blocks 0..15 also pack fp32 weights into MFMA A-fragment layout
// (was k_wfrag; saves one serialized launch in the graph).
// wfrag layout: M = 128 (gate rows 0..63, upd rows 64..127), K = 64.
// lane l holds A[m=16mt+(l&15)][k=32s+8(l>>4)+j], j=0..7 -> 4 dwords.
__global__ __launch_bounds__(256) void k_stats_partial(
        const float* __restrict__ x, float2* __restrict__ part,
        const float* __restrict__ gw, const float* __restrict__ uw,
        uint32_t* __restrict__ wfrag) {
    int blk = blockIdx.x;
    int t = threadIdx.x;
    if (blk < 16) {
        int idx = blk * 256 + t;                  // 0..4095
        int fi = idx >> 8, rem = idx & 255;
        int l = rem >> 2, d = rem & 3;
        int mt = fi >> 1, s = fi & 1;
        int m = 16 * mt + (l & 15);
        int k = 32 * s + 8 * (l >> 4) + 2 * d;
        const float* Wr = (m < 64) ? (gw + m * 64) : (uw + (m - 64) * 64);
        wfrag[idx] = f32_to_bf16_bits(Wr[k]) | (f32_to_bf16_bits(Wr[k + 1]) << 16);
    }
    const float4* p = (const float4*)(x + (size_t)blk * 65536);
    float s = 0.f, s2 = 0.f;
#pragma unroll 16
    for (int i = 0; i < 64; ++i) {
        float4 v = p[t + i * 256];
        s  += v.x + v.y + v.z + v.w;
        s2 += v.x * v.x + v.y * v.y + v.z * v.z + v.w * v.w;
    }
#pragma unroll
    for (int off = 32; off; off >>= 1) {
        s  += __shfl_down(s,  off, 64);
        s2 += __shfl_down(s2, off, 64);
    }
    __shared__ float2 red[4];
    int wid = t >> 6;
    if ((t & 63) == 0) red[wid] = make_float2(s, s2);
    __syncthreads();
    if (t == 0) {
        float a = 0.f, b2 = 0.f;
#pragma unroll
        for (int i = 0; i < 4; ++i) { a += red[i].x; b2 += red[i].y; }
        part[blk] = make_float2(a, b2);
    }
}

// ---------------- K1b: finalize stats -> per-(b,c) affine ------------------
__global__ __launch_bounds__(512) void k_stats_final(
        const float2* __restrict__ part,
        const float* __restrict__ gn_w, const float* __restrict__ gn_b,
        float2* __restrict__ aff) {
    __shared__ float2 st[64];
    int t = threadIdx.x;
    if (t < 64) {
        float s = 0.f, s2 = 0.f;
#pragma unroll
        for (int i = 0; i < 8; ++i) { float2 p = part[t * 8 + i]; s += p.x; s2 += p.y; }
        float inv  = 1.0f / (float)GROUPELEMS;
        float mu   = s * inv;
        float var  = s2 * inv - mu * mu;
        st[t] = make_float2(mu, rsqrtf(var + EPSV));
    }
    __syncthreads();
    int b = t >> 6, c = t & 63, g = c >> 3;
    float2 mr = st[b * 8 + g];
    float a  = mr.y * gn_w[c];
    aff[t] = make_float2(a, gn_b[c] - mr.x * a);
}

// ---------------- K2: MFMA row kernel — norm, convs, sigmoid, W-scan -------
// grid = B*H = 2048 blocks x 256. Two halves of 128 px per row.
// LDS: single overlaid buffer gvhn[128][65] (33280 B) + affs/bgs/bus (1024 B)
//      = 34304 B  -> 4 blocks/CU LDS-wise; VGPR 64 via launch_bounds(256,4).
// pair stores are NON-TEMPORAL: pair is written once, read once by k_hscan;
// bypassing cache retention avoids write-allocate RFO fetches and stops pair
// from evicting x (x+pair footprint = 256 MiB = exactly L3 capacity).
__global__ __launch_bounds__(256, 4) void k_row(
        const float* __restrict__ x,
        const uint32_t* __restrict__ wfrag,
        const float* __restrict__ gate_b, const float* __restrict__ upd_b,
        const float2* __restrict__ aff,
        uint32_t* __restrict__ pair) {
    __shared__ uint32_t gvhn[128 * 65];   // [px][dword], stride 65
    __shared__ float2 affs[64];
    __shared__ __align__(16) float bgs[64];
    __shared__ __align__(16) float bus[64];

    const int t = threadIdx.x;
    const int w = t >> 6, l = t & 63, q = l >> 4, r16 = l & 15;
    const int row = blockIdx.x;
    const int b = row >> 8, y = row & 255;
    const size_t rowoff = (size_t)b * CHW + (size_t)y * WW;

    if (t < 64) { affs[t] = aff[b * 64 + t]; bgs[t] = gate_b[t]; bus[t] = upd_b[t]; }

    // A fragments: 16 coalesced dwordx4 loads (64 VGPRs, live whole kernel)
    bf16x8 A[8][2];
#pragma unroll
    for (int mt = 0; mt < 8; ++mt)
#pragma unroll
        for (int s = 0; s < 2; ++s) {
            U32x4 u;
            u.q = *(const uint4*)(wfrag + (((mt << 1) | s) * 64 + l) * 4);
            A[mt][s] = u.v;
        }
    __syncthreads();

    float s_carry = 0.f;
    for (int tau = 0; tau < 2; ++tau) {
        const int x0 = tau << 7;
        // ---- stage normalized bf16 tile: 8 float4 loads, 16 b32 LDS writes -
        // lane group of 32 shares c2, consecutive p4 -> 512 B coalesced loads
#pragma unroll
        for (int i = 0; i < 4; ++i) {
            int unit = i * 256 + t;          // 0..1023
            int c2 = unit >> 5, p4 = unit & 31;
            int c = c2 << 1, px = p4 << 2;
            const float* xp = x + rowoff + (size_t)c * HWSZ + x0 + px;
            float4 v0 = *(const float4*)xp;
            float4 v1 = *(const float4*)(xp + HWSZ);
            float2 a0 = affs[c], a1 = affs[c + 1];
            uint32_t base = px * 65 + c2;
            gvhn[base]       = f32_to_bf16_bits(v0.x * a0.x + a0.y)
                             | (f32_to_bf16_bits(v1.x * a1.x + a1.y) << 16);
            gvhn[base + 65]  = f32_to_bf16_bits(v0.y * a0.x + a0.y)
                             | (f32_to_bf16_bits(v1.y * a1.x + a1.y) << 16);
            gvhn[base + 130] = f32_to_bf16_bits(v0.z * a0.x + a0.y)
                             | (f32_to_bf16_bits(v1.z * a1.x + a1.y) << 16);
            gvhn[base + 195] = f32_to_bf16_bits(v0.w * a0.x + a0.y)
                             | (f32_to_bf16_bits(v1.w * a1.x + a1.y) << 16);
        }
        __syncthreads();

        // ---- MFMA: wave w owns local px [32w, 32w+32) = 2 N-chunks of 16 ---
#pragma unroll
        for (int nc = 0; nc < 2; ++nc) {
            int n_local = (w << 5) + (nc << 4) + r16;
            int based = n_local * 65 + 4 * q;
            U32x4 B0u, B1u;
#pragma unroll
            for (int d = 0; d < 4; ++d) B0u.u[d] = gvhn[based + d];        // k=8q..8q+7
#pragma unroll
            for (int d = 0; d < 4; ++d) B1u.u[d] = gvhn[based + 16 + d];   // +32
            // acc init = bias, read as aligned f32x4 broadcast from LDS
            f32x4 acc[8];
#pragma unroll
            for (int mt = 0; mt < 4; ++mt) {
                acc[mt]     = *(const f32x4*)(bgs + 16 * mt + 4 * q);
                acc[mt + 4] = *(const f32x4*)(bus + 16 * mt + 4 * q);
            }
#pragma unroll
            for (int mt = 0; mt < 8; ++mt)
                acc[mt] = __builtin_amdgcn_mfma_f32_16x16x32_bf16(A[mt][0], B0u.v, acc[mt], 0, 0, 0);
#pragma unroll
            for (int mt = 0; mt < 8; ++mt)
                acc[mt] = __builtin_amdgcn_mfma_f32_16x16x32_bf16(A[mt][1], B1u.v, acc[mt], 0, 0, 0);
            // epilogue: sigmoid + pack (g | (1-g)*u<<16) via v_perm
#pragma unroll
            for (int mt = 0; mt < 4; ++mt)
#pragma unroll
                for (int r = 0; r < 4; ++r) {
                    float ga = acc[mt][r];
                    float ua = acc[mt + 4][r];
                    float g  = 1.0f / (1.0f + __expf(-ga));
                    float vv = (1.0f - g) * ua;
                    uint32_t pk = __builtin_amdgcn_perm(__float_as_uint(vv),
                                                        __float_as_uint(g), 0x07060302u);
                    gvhn[n_local * 65 + 16 * mt + 4 * q + r] = pk;
                }
        }
        __syncthreads();

        // ---- W-scan: thread c (<64) serial over 128 px; banks 2-way -------
        if (t < 64) {
            float s = s_carry;
#pragma unroll 8
            for (int xi = 0; xi < 128; ++xi) {
                uint32_t pk = gvhn[xi * 65 + t];
                float g = __uint_as_float(pk << 16);
                float v = __uint_as_float(pk & 0xffff0000u);
                s = __builtin_fmaf(g, s, v);
                gvhn[xi * 65 + t] = __builtin_amdgcn_perm(__float_as_uint(s), pk, 0x07060100u);
            }
            s_carry = s;
        }
        __syncthreads();

        // ---- write packed (gate, hw): 8 x NT dwordx4 stores, coalesced ----
#pragma unroll
        for (int i = 0; i < 8; ++i) {
            int unit = i * 256 + t;          // 0..2047
            int c = unit >> 5, p4 = unit & 31;
            int px = p4 << 2;
            uint32_t bidx = px * 65 + c;
            u32x4 o;
            o.x = gvhn[bidx];
            o.y = gvhn[bidx + 65];
            o.z = gvhn[bidx + 130];
            o.w = gvhn[bidx + 195];
            __builtin_nontemporal_store(o,
                (u32x4*)(pair + rowoff + (size_t)c * HWSZ + x0 + px));
        }
        __syncthreads();
    }
}

// ---------------- K3: H-scan + residual, prefetched, in-place on d_out -----
// All traffic here is streaming (pair read once, x read for the last time,
// out read by nobody) -> non-temporal loads and stores throughout.
__global__ __launch_bounds__(256) void k_hscan(
        uint32_t* __restrict__ io, const float* __restrict__ x) {
    int t = threadIdx.x;
    size_t base = (size_t)blockIdx.x * HWSZ + t;
    uint32_t pk[16]; float xv[16];
#pragma unroll
    for (int j = 0; j < 16; ++j) pk[j] = __builtin_nontemporal_load(io + base + (size_t)j * WW);
#pragma unroll
    for (int j = 0; j < 16; ++j) xv[j] = __builtin_nontemporal_load(x + base + (size_t)j * WW);
    float s = 0.f;
    for (int yt = 0; yt < 16; ++yt) {
        uint32_t npk[16]; float nxv[16];
        if (yt < 15) {                       // prefetch next 16-row group
            size_t nb = base + (size_t)(yt + 1) * 16 * WW;
#pragma unroll
            for (int j = 0; j < 16; ++j) npk[j] = __builtin_nontemporal_load(io + nb + (size_t)j * WW);
#pragma unroll
            for (int j = 0; j < 16; ++j) nxv[j] = __builtin_nontemporal_load(x + nb + (size_t)j * WW);
        }
        float gj[16], vj[16];                // hoist unpack out of serial chain
#pragma unroll
        for (int j = 0; j < 16; ++j) {
            float g   = __uint_as_float(pk[j] << 16);
            float hwv = __uint_as_float(pk[j] & 0xffff0000u);
            gj[j] = g; vj[j] = (1.f - g) * hwv;
        }
        float res[16];
#pragma unroll
        for (int j = 0; j < 16; ++j) { s = __builtin_fmaf(gj[j], s, vj[j]); res[j] = xv[j] + s; }
        size_t ob = base + (size_t)yt * 16 * WW;
#pragma unroll
        for (int j = 0; j < 16; ++j)
            __builtin_nontemporal_store(__float_as_uint(res[j]), io + ob + (size_t)j * WW);
#pragma unroll
        for (int j = 0; j < 16; ++j) { pk[j] = npk[j]; xv[j] = nxv[j]; }
    }
}

extern "C" void kernel_launch(void* const* d_in, const int* in_sizes, int n_in,
                              void* d_out, int out_size, void* d_ws, size_t ws_size,
                              hipStream_t stream) {
    const float* x      = (const float*)d_in[0];
    const float* gn_w   = (const float*)d_in[1];
    const float* gn_b   = (const float*)d_in[2];
    const float* gate_w = (const float*)d_in[3];
    const float* gate_b = (const float*)d_in[4];
    const float* upd_w  = (const float*)d_in[5];
    const float* upd_b  = (const float*)d_in[6];

    char* ws = (char*)d_ws;
    float2*   part  = (float2*)(ws + WS_PART_OFF);
    float2*   aff   = (float2*)(ws + WS_AFF_OFF);
    uint32_t* wfrag = (uint32_t*)(ws + WS_WFRAG_OFF);
    uint32_t* pair  = (uint32_t*)d_out;   // packed (gate,hw); K3 rewrites in place

    k_stats_partial<<<512, 256, 0, stream>>>(x, part, gate_w, upd_w, wfrag);
    k_stats_final<<<1, 512, 0, stream>>>(part, gn_w, gn_b, aff);
    k_row<<<BB * HH, 256, 0, stream>>>(x, wfrag, gate_b, upd_b, aff, pair);
    k_hscan<<<BB * CC, 256, 0, stream>>>(pair, x);
}

// Round 4
// 386.783 us; speedup vs baseline: 1.1582x; 1.0257x over previous
//
#include <hip/hip_runtime.h>
#include <stdint.h>

// Problem constants
#define BB   8
#define CC   64
#define HH   256
#define WW   256
#define HWSZ (HH*WW)              // 65536
#define CHW  (CC*HH*WW)           // 4194304
#define GROUPELEMS (8*HWSZ)       // 524288 (channels-per-group=8)
#define EPSV 1e-5f

// ws layout (bytes)
#define WS_PART_OFF   0           // 512 x float2   (4 KiB)
#define WS_AFF_OFF    4096        // 512 x float2   (4 KiB)
#define WS_WFRAG_OFF  8192        // 4096 x uint32  (16 KiB)  A-fragment packed weights
#define WS_CARRY_OFF  32768       // 2048*256 float2 (4 MiB)  per-(img,seg,col) aggregate
#define WS_SIN_OFF    4227072     // 2048*256 float  (2 MiB)  per-(img,seg,col) incoming carry
#define WS_NEED       6324224

typedef __attribute__((ext_vector_type(8))) short bf16x8;
typedef __attribute__((ext_vector_type(4))) float f32x4;
typedef __attribute__((ext_vector_type(4))) unsigned int u32x4;  // native vec for NT store
union U32x4 { uint32_t u[4]; uint4 q; bf16x8 v; u32x4 nv; };

__device__ __forceinline__ uint32_t f32_to_bf16_bits(float f) {
    uint32_t u = __float_as_uint(f);
    u += 0x7fffu + ((u >> 16) & 1u);   // RNE
    return u >> 16;
}

// ---------------- K1: per-slice partial sums for GroupNorm stats ------------
// Fused: blocks 0..15 also pack fp32 weights into MFMA A-fragment layout.
// wfrag layout: M = 128 (gate rows 0..63, upd rows 64..127), K = 64.
// lane l holds A[m=16mt+(l&15)][k=32s+8(l>>4)+j], j=0..7 -> 4 dwords.
__global__ __launch_bounds__(256) void k_stats_partial(
        const float* __restrict__ x, float2* __restrict__ part,
        const float* __restrict__ gw, const float* __restrict__ uw,
        uint32_t* __restrict__ wfrag) {
    int blk = blockIdx.x;
    int t = threadIdx.x;
    if (blk < 16) {
        int idx = blk * 256 + t;                  // 0..4095
        int fi = idx >> 8, rem = idx & 255;
        int l = rem >> 2, d = rem & 3;
        int mt = fi >> 1, s = fi & 1;
        int m = 16 * mt + (l & 15);
        int k = 32 * s + 8 * (l >> 4) + 2 * d;
        const float* Wr = (m < 64) ? (gw + m * 64) : (uw + (m - 64) * 64);
        wfrag[idx] = f32_to_bf16_bits(Wr[k]) | (f32_to_bf16_bits(Wr[k + 1]) << 16);
    }
    const float4* p = (const float4*)(x + (size_t)blk * 65536);
    float s = 0.f, s2 = 0.f;
#pragma unroll 16
    for (int i = 0; i < 64; ++i) {
        float4 v = p[t + i * 256];
        s  += v.x + v.y + v.z + v.w;
        s2 += v.x * v.x + v.y * v.y + v.z * v.z + v.w * v.w;
    }
#pragma unroll
    for (int off = 32; off; off >>= 1) {
        s  += __shfl_down(s,  off, 64);
        s2 += __shfl_down(s2, off, 64);
    }
    __shared__ float2 red[4];
    int wid = t >> 6;
    if ((t & 63) == 0) red[wid] = make_float2(s, s2);
    __syncthreads();
    if (t == 0) {
        float a = 0.f, b2 = 0.f;
#pragma unroll
        for (int i = 0; i < 4; ++i) { a += red[i].x; b2 += red[i].y; }
        part[blk] = make_float2(a, b2);
    }
}

// ---------------- K1b: finalize stats -> per-(b,c) affine ------------------
__global__ __launch_bounds__(512) void k_stats_final(
        const float2* __restrict__ part,
        const float* __restrict__ gn_w, const float* __restrict__ gn_b,
        float2* __restrict__ aff) {
    __shared__ float2 st[64];
    int t = threadIdx.x;
    if (t < 64) {
        float s = 0.f, s2 = 0.f;
#pragma unroll
        for (int i = 0; i < 8; ++i) { float2 p = part[t * 8 + i]; s += p.x; s2 += p.y; }
        float inv  = 1.0f / (float)GROUPELEMS;
        float mu   = s * inv;
        float var  = s2 * inv - mu * mu;
        st[t] = make_float2(mu, rsqrtf(var + EPSV));
    }
    __syncthreads();
    int b = t >> 6, c = t & 63, g = c >> 3;
    float2 mr = st[b * 8 + g];
    float a  = mr.y * gn_w[c];
    aff[t] = make_float2(a, gn_b[c] - mr.x * a);
}

// ---------------- K2: MFMA row kernel — norm, convs, sigmoid, W-scan -------
// grid = B*H = 2048 blocks x 256. Two halves of 128 px per row.
// LDS: gvhn[128][65] (33280 B) + affs/bgs/bus (1024 B) = 34304 B -> 4 blk/CU.
// SPILL FIX (round 4): A fragments are NOT held resident (was 64 VGPRs ->
// spills at launch_bounds(256,4): VGPR_Count=64, +176 MiB scratch writes).
// Instead stream them from global wfrag (16 KiB, L1-hot) per nc-chunk, with
// an asm-laundered pointer so LICM cannot hoist the loads back to residency.
__global__ __launch_bounds__(256, 4) void k_row(
        const float* __restrict__ x,
        const uint32_t* __restrict__ wfrag,
        const float* __restrict__ gate_b, const float* __restrict__ upd_b,
        const float2* __restrict__ aff,
        uint32_t* __restrict__ pair) {
    __shared__ uint32_t gvhn[128 * 65];   // [px][dword], stride 65
    __shared__ float2 affs[64];
    __shared__ __align__(16) float bgs[64];
    __shared__ __align__(16) float bus[64];

    const int t = threadIdx.x;
    const int w = t >> 6, l = t & 63, q = l >> 4, r16 = l & 15;
    const int row = blockIdx.x;
    const int b = row >> 8, y = row & 255;
    const size_t rowoff = (size_t)b * CHW + (size_t)y * WW;

    if (t < 64) { affs[t] = aff[b * 64 + t]; bgs[t] = gate_b[t]; bus[t] = upd_b[t]; }
    __syncthreads();

    float s_carry = 0.f;
    for (int tau = 0; tau < 2; ++tau) {
        const int x0 = tau << 7;
        // ---- stage normalized bf16 tile: 8 float4 loads, 16 b32 LDS writes -
#pragma unroll
        for (int i = 0; i < 4; ++i) {
            int unit = i * 256 + t;          // 0..1023
            int c2 = unit >> 5, p4 = unit & 31;
            int c = c2 << 1, px = p4 << 2;
            const float* xp = x + rowoff + (size_t)c * HWSZ + x0 + px;
            float4 v0 = *(const float4*)xp;
            float4 v1 = *(const float4*)(xp + HWSZ);
            float2 a0 = affs[c], a1 = affs[c + 1];
            uint32_t base = px * 65 + c2;
            gvhn[base]       = f32_to_bf16_bits(v0.x * a0.x + a0.y)
                             | (f32_to_bf16_bits(v1.x * a1.x + a1.y) << 16);
            gvhn[base + 65]  = f32_to_bf16_bits(v0.y * a0.x + a0.y)
                             | (f32_to_bf16_bits(v1.y * a1.x + a1.y) << 16);
            gvhn[base + 130] = f32_to_bf16_bits(v0.z * a0.x + a0.y)
                             | (f32_to_bf16_bits(v1.z * a1.x + a1.y) << 16);
            gvhn[base + 195] = f32_to_bf16_bits(v0.w * a0.x + a0.y)
                             | (f32_to_bf16_bits(v1.w * a1.x + a1.y) << 16);
        }
        __syncthreads();

        // ---- MFMA: wave w owns local px [32w, 32w+32) = 2 N-chunks of 16 ---
#pragma unroll
        for (int nc = 0; nc < 2; ++nc) {
            int n_local = (w << 5) + (nc << 4) + r16;
            int based = n_local * 65 + 4 * q;
            U32x4 B0u, B1u;
#pragma unroll
            for (int d = 0; d < 4; ++d) B0u.u[d] = gvhn[based + d];        // k=8q..8q+7
#pragma unroll
            for (int d = 0; d < 4; ++d) B1u.u[d] = gvhn[based + 16 + d];   // +32
            // acc init = bias, read as aligned f32x4 broadcast from LDS
            f32x4 acc[8];
#pragma unroll
            for (int mt = 0; mt < 4; ++mt) {
                acc[mt]     = *(const f32x4*)(bgs + 16 * mt + 4 * q);
                acc[mt + 4] = *(const f32x4*)(bus + 16 * mt + 4 * q);
            }
            // laundered pointer: loads below cannot be hoisted out of nc/tau
            uintptr_t wfa = (uintptr_t)wfrag;
            asm volatile("" : "+s"(wfa));
            const uint32_t* wf = (const uint32_t*)wfa;
#pragma unroll
            for (int mt = 0; mt < 8; ++mt) {
                U32x4 a0, a1;
                a0.q = *(const uint4*)(wf + (((mt << 1) | 0) * 64 + l) * 4);
                a1.q = *(const uint4*)(wf + (((mt << 1) | 1) * 64 + l) * 4);
                acc[mt] = __builtin_amdgcn_mfma_f32_16x16x32_bf16(a0.v, B0u.v, acc[mt], 0, 0, 0);
                acc[mt] = __builtin_amdgcn_mfma_f32_16x16x32_bf16(a1.v, B1u.v, acc[mt], 0, 0, 0);
            }
            // epilogue: sigmoid + pack (g | (1-g)*u<<16) via v_perm
#pragma unroll
            for (int mt = 0; mt < 4; ++mt)
#pragma unroll
                for (int r = 0; r < 4; ++r) {
                    float ga = acc[mt][r];
                    float ua = acc[mt + 4][r];
                    float g  = 1.0f / (1.0f + __expf(-ga));
                    float vv = (1.0f - g) * ua;
                    uint32_t pk = __builtin_amdgcn_perm(__float_as_uint(vv),
                                                        __float_as_uint(g), 0x07060302u);
                    gvhn[n_local * 65 + 16 * mt + 4 * q + r] = pk;
                }
        }
        __syncthreads();

        // ---- W-scan: thread c (<64) serial over 128 px; banks 2-way -------
        if (t < 64) {
            float s = s_carry;
#pragma unroll 8
            for (int xi = 0; xi < 128; ++xi) {
                uint32_t pk = gvhn[xi * 65 + t];
                float g = __uint_as_float(pk << 16);
                float v = __uint_as_float(pk & 0xffff0000u);
                s = __builtin_fmaf(g, s, v);
                gvhn[xi * 65 + t] = __builtin_amdgcn_perm(__float_as_uint(s), pk, 0x07060100u);
            }
            s_carry = s;
        }
        __syncthreads();

        // ---- write packed (gate, hw): 8 x NT dwordx4 stores, coalesced ----
#pragma unroll
        for (int i = 0; i < 8; ++i) {
            int unit = i * 256 + t;          // 0..2047
            int c = unit >> 5, p4 = unit & 31;
            int px = p4 << 2;
            uint32_t bidx = px * 65 + c;
            u32x4 o;
            o.x = gvhn[bidx];
            o.y = gvhn[bidx + 65];
            o.z = gvhn[bidx + 130];
            o.w = gvhn[bidx + 195];
            __builtin_nontemporal_store(o,
                (u32x4*)(pair + rowoff + (size_t)c * HWSZ + x0 + px));
        }
        __syncthreads();
    }
}

// ---------------- K3 (segmented): H-scan as aggregate/compose/apply --------
// Parallelism fix: old k_hscan had 512 blocks (2 waves/SIMD). Split H into
// 4 segments of 64 rows -> 2048 blocks (8 blocks/CU). Same recurrence:
// segment transform s_out = G*s_in + V, G = prod g, V = local scan of (1-g)hw.

// K3a: per-(img,seg,col) aggregate (G, V). Temporal loads keep pair in L2/L3
// for K3c's re-read.
__global__ __launch_bounds__(256) void k_hseg_agg(
        const uint32_t* __restrict__ io, float2* __restrict__ carry) {
    int blk = blockIdx.x;                 // img*4 + seg
    int t = threadIdx.x;                  // column
    size_t base = (size_t)(blk >> 2) * HWSZ + (size_t)(blk & 3) * 64 * WW + t;
    float G = 1.f, V = 0.f;
    uint32_t pk[16];
#pragma unroll
    for (int j = 0; j < 16; ++j) pk[j] = io[base + (size_t)j * WW];
    for (int grp = 0; grp < 4; ++grp) {
        uint32_t npk[16];
        if (grp < 3) {
            size_t nb = base + (size_t)(grp + 1) * 16 * WW;
#pragma unroll
            for (int j = 0; j < 16; ++j) npk[j] = io[nb + (size_t)j * WW];
        }
#pragma unroll
        for (int j = 0; j < 16; ++j) {
            float g  = __uint_as_float(pk[j] << 16);
            float hw = __uint_as_float(pk[j] & 0xffff0000u);
            V = __builtin_fmaf(g, V, (1.f - g) * hw);
            G *= g;
        }
#pragma unroll
        for (int j = 0; j < 16; ++j) pk[j] = npk[j];
    }
    carry[(size_t)blk * 256 + t] = make_float2(G, V);
}

// K3b: compose 4 segment aggregates per column -> incoming carry per segment.
__global__ __launch_bounds__(256) void k_hseg_fix(
        const float2* __restrict__ carry, float* __restrict__ sin_) {
    int t = threadIdx.x;
    size_t cb = (size_t)blockIdx.x * 1024 + t;   // img*4*256 + col
    float s = 0.f;
#pragma unroll
    for (int seg = 0; seg < 4; ++seg) {
        sin_[cb + seg * 256] = s;
        float2 gv = carry[cb + seg * 256];
        s = __builtin_fmaf(gv.x, s, gv.y);
    }
}

// K3c: apply scan from incoming carry + residual, in-place on d_out.
// All streaming traffic (last uses) -> non-temporal.
__global__ __launch_bounds__(256) void k_hseg_apply(
        uint32_t* __restrict__ io, const float* __restrict__ x,
        const float* __restrict__ sin_) {
    int blk = blockIdx.x;                 // img*4 + seg
    int t = threadIdx.x;
    size_t base = (size_t)(blk >> 2) * HWSZ + (size_t)(blk & 3) * 64 * WW + t;
    float s = sin_[(size_t)blk * 256 + t];
    uint32_t pk[16]; float xv[16];
#pragma unroll
    for (int j = 0; j < 16; ++j) pk[j] = __builtin_nontemporal_load(io + base + (size_t)j * WW);
#pragma unroll
    for (int j = 0; j < 16; ++j) xv[j] = __builtin_nontemporal_load(x + base + (size_t)j * WW);
    for (int grp = 0; grp < 4; ++grp) {
        uint32_t npk[16]; float nxv[16];
        if (grp < 3) {
            size_t nb = base + (size_t)(grp + 1) * 16 * WW;
#pragma unroll
            for (int j = 0; j < 16; ++j) npk[j] = __builtin_nontemporal_load(io + nb + (size_t)j * WW);
#pragma unroll
            for (int j = 0; j < 16; ++j) nxv[j] = __builtin_nontemporal_load(x + nb + (size_t)j * WW);
        }
        float gj[16], vj[16];
#pragma unroll
        for (int j = 0; j < 16; ++j) {
            float g   = __uint_as_float(pk[j] << 16);
            float hwv = __uint_as_float(pk[j] & 0xffff0000u);
            gj[j] = g; vj[j] = (1.f - g) * hwv;
        }
        float res[16];
#pragma unroll
        for (int j = 0; j < 16; ++j) { s = __builtin_fmaf(gj[j], s, vj[j]); res[j] = xv[j] + s; }
        size_t ob = base + (size_t)grp * 16 * WW;
#pragma unroll
        for (int j = 0; j < 16; ++j)
            __builtin_nontemporal_store(__float_as_uint(res[j]), io + ob + (size_t)j * WW);
#pragma unroll
        for (int j = 0; j < 16; ++j) { pk[j] = npk[j]; xv[j] = nxv[j]; }
    }
}

// ---------------- K3 (fallback): monolithic H-scan if ws too small ---------
__global__ __launch_bounds__(256) void k_hscan(
        uint32_t* __restrict__ io, const float* __restrict__ x) {
    int t = threadIdx.x;
    size_t base = (size_t)blockIdx.x * HWSZ + t;
    uint32_t pk[16]; float xv[16];
#pragma unroll
    for (int j = 0; j < 16; ++j) pk[j] = __builtin_nontemporal_load(io + base + (size_t)j * WW);
#pragma unroll
    for (int j = 0; j < 16; ++j) xv[j] = __builtin_nontemporal_load(x + base + (size_t)j * WW);
    float s = 0.f;
    for (int yt = 0; yt < 16; ++yt) {
        uint32_t npk[16]; float nxv[16];
        if (yt < 15) {
            size_t nb = base + (size_t)(yt + 1) * 16 * WW;
#pragma unroll
            for (int j = 0; j < 16; ++j) npk[j] = __builtin_nontemporal_load(io + nb + (size_t)j * WW);
#pragma unroll
            for (int j = 0; j < 16; ++j) nxv[j] = __builtin_nontemporal_load(x + nb + (size_t)j * WW);
        }
        float gj[16], vj[16];
#pragma unroll
        for (int j = 0; j < 16; ++j) {
            float g   = __uint_as_float(pk[j] << 16);
            float hwv = __uint_as_float(pk[j] & 0xffff0000u);
            gj[j] = g; vj[j] = (1.f - g) * hwv;
        }
        float res[16];
#pragma unroll
        for (int j = 0; j < 16; ++j) { s = __builtin_fmaf(gj[j], s, vj[j]); res[j] = xv[j] + s; }
        size_t ob = base + (size_t)yt * 16 * WW;
#pragma unroll
        for (int j = 0; j < 16; ++j)
            __builtin_nontemporal_store(__float_as_uint(res[j]), io + ob + (size_t)j * WW);
#pragma unroll
        for (int j = 0; j < 16; ++j) { pk[j] = npk[j]; xv[j] = nxv[j]; }
    }
}

extern "C" void kernel_launch(void* const* d_in, const int* in_sizes, int n_in,
                              void* d_out, int out_size, void* d_ws, size_t ws_size,
                              hipStream_t stream) {
    const float* x      = (const float*)d_in[0];
    const float* gn_w   = (const float*)d_in[1];
    const float* gn_b   = (const float*)d_in[2];
    const float* gate_w = (const float*)d_in[3];
    const float* gate_b = (const float*)d_in[4];
    const float* upd_w  = (const float*)d_in[5];
    const float* upd_b  = (const float*)d_in[6];

    char* ws = (char*)d_ws;
    float2*   part  = (float2*)(ws + WS_PART_OFF);
    float2*   aff   = (float2*)(ws + WS_AFF_OFF);
    uint32_t* wfrag = (uint32_t*)(ws + WS_WFRAG_OFF);
    uint32_t* pair  = (uint32_t*)d_out;   // packed (gate,hw); K3 rewrites in place

    k_stats_partial<<<512, 256, 0, stream>>>(x, part, gate_w, upd_w, wfrag);
    k_stats_final<<<1, 512, 0, stream>>>(part, gn_w, gn_b, aff);
    k_row<<<BB * HH, 256, 0, stream>>>(x, wfrag, gate_b, upd_b, aff, pair);

    if (ws_size >= (size_t)WS_NEED) {
        float2* carry = (float2*)(ws + WS_CARRY_OFF);
        float*  sin_  = (float*)(ws + WS_SIN_OFF);
        k_hseg_agg<<<BB * CC * 4, 256, 0, stream>>>(pair, carry);
        k_hseg_fix<<<BB * CC, 256, 0, stream>>>(carry, sin_);
        k_hseg_apply<<<BB * CC * 4, 256, 0, stream>>>(pair, x, sin_);
    } else {
        k_hscan<<<BB * CC, 256, 0, stream>>>(pair, x);
    }
}

// Round 5
// 360.584 us; speedup vs baseline: 1.2423x; 1.0727x over previous
//
#include <hip/hip_runtime.h>
#include <stdint.h>

// Problem constants
#define BB   8
#define CC   64
#define HH   256
#define WW   256
#define HWSZ (HH*WW)              // 65536
#define CHW  (CC*HH*WW)           // 4194304
#define GROUPELEMS (8*HWSZ)       // 524288 (channels-per-group=8)
#define EPSV 1e-5f

// ws layout (bytes)
#define WS_PART_OFF   0           // 512 x float2   (4 KiB)
#define WS_AFF_OFF    4096        // 512 x float2   (4 KiB)
#define WS_WFRAG_OFF  8192        // 4096 x uint32  (16 KiB)  A-fragment packed weights

typedef __attribute__((ext_vector_type(8))) short bf16x8;
typedef __attribute__((ext_vector_type(4))) float f32x4;
typedef __attribute__((ext_vector_type(4))) unsigned int u32x4;
union U32x4 { uint32_t u[4]; uint4 q; bf16x8 v; u32x4 nv; };

__device__ __forceinline__ uint32_t f32_to_bf16_bits(float f) {
    uint32_t u = __float_as_uint(f);
    u += 0x7fffu + ((u >> 16) & 1u);   // RNE
    return u >> 16;
}

// ---------------- K1: per-slice partial sums for GroupNorm stats ------------
// Fused: blocks 0..15 also pack fp32 weights into MFMA A-fragment layout.
// wfrag layout: M = 128 (gate rows 0..63, upd rows 64..127), K = 64.
// lane l holds A[m=16mt+(l&15)][k=32s+8(l>>4)+j], j=0..7 -> 4 dwords.
__global__ __launch_bounds__(256) void k_stats_partial(
        const float* __restrict__ x, float2* __restrict__ part,
        const float* __restrict__ gw, const float* __restrict__ uw,
        uint32_t* __restrict__ wfrag) {
    int blk = blockIdx.x;
    int t = threadIdx.x;
    if (blk < 16) {
        int idx = blk * 256 + t;                  // 0..4095
        int fi = idx >> 8, rem = idx & 255;
        int l = rem >> 2, d = rem & 3;
        int mt = fi >> 1, s = fi & 1;
        int m = 16 * mt + (l & 15);
        int k = 32 * s + 8 * (l >> 4) + 2 * d;
        const float* Wr = (m < 64) ? (gw + m * 64) : (uw + (m - 64) * 64);
        wfrag[idx] = f32_to_bf16_bits(Wr[k]) | (f32_to_bf16_bits(Wr[k + 1]) << 16);
    }
    const float4* p = (const float4*)(x + (size_t)blk * 65536);
    float s = 0.f, s2 = 0.f;
#pragma unroll 16
    for (int i = 0; i < 64; ++i) {
        float4 v = p[t + i * 256];
        s  += v.x + v.y + v.z + v.w;
        s2 += v.x * v.x + v.y * v.y + v.z * v.z + v.w * v.w;
    }
#pragma unroll
    for (int off = 32; off; off >>= 1) {
        s  += __shfl_down(s,  off, 64);
        s2 += __shfl_down(s2, off, 64);
    }
    __shared__ float2 red[4];
    int wid = t >> 6;
    if ((t & 63) == 0) red[wid] = make_float2(s, s2);
    __syncthreads();
    if (t == 0) {
        float a = 0.f, b2 = 0.f;
#pragma unroll
        for (int i = 0; i < 4; ++i) { a += red[i].x; b2 += red[i].y; }
        part[blk] = make_float2(a, b2);
    }
}

// ---------------- K1b: finalize stats -> per-(b,c) affine ------------------
__global__ __launch_bounds__(512) void k_stats_final(
        const float2* __restrict__ part,
        const float* __restrict__ gn_w, const float* __restrict__ gn_b,
        float2* __restrict__ aff) {
    __shared__ float2 st[64];
    int t = threadIdx.x;
    if (t < 64) {
        float s = 0.f, s2 = 0.f;
#pragma unroll
        for (int i = 0; i < 8; ++i) { float2 p = part[t * 8 + i]; s += p.x; s2 += p.y; }
        float inv  = 1.0f / (float)GROUPELEMS;
        float mu   = s * inv;
        float var  = s2 * inv - mu * mu;
        st[t] = make_float2(mu, rsqrtf(var + EPSV));
    }
    __syncthreads();
    int b = t >> 6, c = t & 63, g = c >> 3;
    float2 mr = st[b * 8 + g];
    float a  = mr.y * gn_w[c];
    aff[t] = make_float2(a, gn_b[c] - mr.x * a);
}

// ---------------- K2: MFMA row kernel — norm, convs, sigmoid, W-scan -------
// grid = B*H = 2048 blocks x 256. Two halves of 128 px per row.
// LDS: gvhn[128][65] (33280 B) + affs/bgs/bus (1024 B) = 34304 B -> 4 blk/CU.
// A fragments streamed from global wfrag (16 KiB, L1-hot) per nc-chunk with
// asm-laundered pointer (resident A-array spilled at launch_bounds(256,4)).
// pair stores TEMPORAL (round 5): L3 retains pair for k_hscan2's phase 1.
__global__ __launch_bounds__(256, 4) void k_row(
        const float* __restrict__ x,
        const uint32_t* __restrict__ wfrag,
        const float* __restrict__ gate_b, const float* __restrict__ upd_b,
        const float2* __restrict__ aff,
        uint32_t* __restrict__ pair) {
    __shared__ uint32_t gvhn[128 * 65];   // [px][dword], stride 65
    __shared__ float2 affs[64];
    __shared__ __align__(16) float bgs[64];
    __shared__ __align__(16) float bus[64];

    const int t = threadIdx.x;
    const int w = t >> 6, l = t & 63, q = l >> 4, r16 = l & 15;
    const int row = blockIdx.x;
    const int b = row >> 8, y = row & 255;
    const size_t rowoff = (size_t)b * CHW + (size_t)y * WW;

    if (t < 64) { affs[t] = aff[b * 64 + t]; bgs[t] = gate_b[t]; bus[t] = upd_b[t]; }
    __syncthreads();

    float s_carry = 0.f;
    for (int tau = 0; tau < 2; ++tau) {
        const int x0 = tau << 7;
        // ---- stage normalized bf16 tile: 8 float4 loads, 16 b32 LDS writes -
#pragma unroll
        for (int i = 0; i < 4; ++i) {
            int unit = i * 256 + t;          // 0..1023
            int c2 = unit >> 5, p4 = unit & 31;
            int c = c2 << 1, px = p4 << 2;
            const float* xp = x + rowoff + (size_t)c * HWSZ + x0 + px;
            float4 v0 = *(const float4*)xp;
            float4 v1 = *(const float4*)(xp + HWSZ);
            float2 a0 = affs[c], a1 = affs[c + 1];
            uint32_t base = px * 65 + c2;
            gvhn[base]       = f32_to_bf16_bits(v0.x * a0.x + a0.y)
                             | (f32_to_bf16_bits(v1.x * a1.x + a1.y) << 16);
            gvhn[base + 65]  = f32_to_bf16_bits(v0.y * a0.x + a0.y)
                             | (f32_to_bf16_bits(v1.y * a1.x + a1.y) << 16);
            gvhn[base + 130] = f32_to_bf16_bits(v0.z * a0.x + a0.y)
                             | (f32_to_bf16_bits(v1.z * a1.x + a1.y) << 16);
            gvhn[base + 195] = f32_to_bf16_bits(v0.w * a0.x + a0.y)
                             | (f32_to_bf16_bits(v1.w * a1.x + a1.y) << 16);
        }
        __syncthreads();

        // ---- MFMA: wave w owns local px [32w, 32w+32) = 2 N-chunks of 16 ---
#pragma unroll
        for (int nc = 0; nc < 2; ++nc) {
            int n_local = (w << 5) + (nc << 4) + r16;
            int based = n_local * 65 + 4 * q;
            U32x4 B0u, B1u;
#pragma unroll
            for (int d = 0; d < 4; ++d) B0u.u[d] = gvhn[based + d];        // k=8q..8q+7
#pragma unroll
            for (int d = 0; d < 4; ++d) B1u.u[d] = gvhn[based + 16 + d];   // +32
            // acc init = bias, read as aligned f32x4 broadcast from LDS
            f32x4 acc[8];
#pragma unroll
            for (int mt = 0; mt < 4; ++mt) {
                acc[mt]     = *(const f32x4*)(bgs + 16 * mt + 4 * q);
                acc[mt + 4] = *(const f32x4*)(bus + 16 * mt + 4 * q);
            }
            // laundered pointer: loads below cannot be hoisted out of nc/tau
            uintptr_t wfa = (uintptr_t)wfrag;
            asm volatile("" : "+s"(wfa));
            const uint32_t* wf = (const uint32_t*)wfa;
#pragma unroll
            for (int mt = 0; mt < 8; ++mt) {
                U32x4 a0, a1;
                a0.q = *(const uint4*)(wf + (((mt << 1) | 0) * 64 + l) * 4);
                a1.q = *(const uint4*)(wf + (((mt << 1) | 1) * 64 + l) * 4);
                acc[mt] = __builtin_amdgcn_mfma_f32_16x16x32_bf16(a0.v, B0u.v, acc[mt], 0, 0, 0);
                acc[mt] = __builtin_amdgcn_mfma_f32_16x16x32_bf16(a1.v, B1u.v, acc[mt], 0, 0, 0);
            }
            // epilogue: sigmoid + pack (g | (1-g)*u<<16) via v_perm
#pragma unroll
            for (int mt = 0; mt < 4; ++mt)
#pragma unroll
                for (int r = 0; r < 4; ++r) {
                    float ga = acc[mt][r];
                    float ua = acc[mt + 4][r];
                    float g  = 1.0f / (1.0f + __expf(-ga));
                    float vv = (1.0f - g) * ua;
                    uint32_t pk = __builtin_amdgcn_perm(__float_as_uint(vv),
                                                        __float_as_uint(g), 0x07060302u);
                    gvhn[n_local * 65 + 16 * mt + 4 * q + r] = pk;
                }
        }
        __syncthreads();

        // ---- W-scan: thread c (<64) serial over 128 px; banks 2-way -------
        if (t < 64) {
            float s = s_carry;
#pragma unroll 8
            for (int xi = 0; xi < 128; ++xi) {
                uint32_t pk = gvhn[xi * 65 + t];
                float g = __uint_as_float(pk << 16);
                float v = __uint_as_float(pk & 0xffff0000u);
                s = __builtin_fmaf(g, s, v);
                gvhn[xi * 65 + t] = __builtin_amdgcn_perm(__float_as_uint(s), pk, 0x07060100u);
            }
            s_carry = s;
        }
        __syncthreads();

        // ---- write packed (gate, hw): 8 x dwordx4 stores, coalesced -------
#pragma unroll
        for (int i = 0; i < 8; ++i) {
            int unit = i * 256 + t;          // 0..2047
            int c = unit >> 5, p4 = unit & 31;
            int px = p4 << 2;
            uint32_t bidx = px * 65 + c;
            u32x4 o;
            o.x = gvhn[bidx];
            o.y = gvhn[bidx + 65];
            o.z = gvhn[bidx + 130];
            o.w = gvhn[bidx + 195];
            *(u32x4*)(pair + rowoff + (size_t)c * HWSZ + x0 + px) = o;
        }
        __syncthreads();
    }
}

// ---------------- K3: fused segmented H-scan + residual, one kernel --------
// One block per (b,c) image: 1024 threads = (col 0..255) x (seg 0..3), each
// thread owns 64 rows. Phase 1: per-segment aggregate (G = prod g,
// V = local scan). LDS compose -> incoming carry per (seg,col). Phase 2:
// re-read pair (block's own 256 KiB, L2/L3-warm) + x, apply, NT store out.
// vs old mono k_hscan: 16 waves/CU (2x), serial depth 64 (4x shorter),
// no extra kernel boundaries. In-place safe: each element's phase-2 read
// and write belong to the same thread, read precedes write in program order.
__global__ __launch_bounds__(1024) void k_hscan2(
        uint32_t* __restrict__ io, const float* __restrict__ x) {
    __shared__ float2 gvs[4][256];
    __shared__ float  sins[4][256];
    const int t = threadIdx.x;
    const int col = t & 255, seg = t >> 8;
    const size_t base = (size_t)blockIdx.x * HWSZ + (size_t)seg * 64 * WW + col;

    // phase 1: segment aggregate (G, V) over 64 rows
    float G = 1.f, V = 0.f;
    for (int grp = 0; grp < 4; ++grp) {
        uint32_t pk[16];
        size_t gb = base + (size_t)grp * 16 * WW;
#pragma unroll
        for (int j = 0; j < 16; ++j) pk[j] = io[gb + (size_t)j * WW];
#pragma unroll
        for (int j = 0; j < 16; ++j) {
            float g  = __uint_as_float(pk[j] << 16);
            float hw = __uint_as_float(pk[j] & 0xffff0000u);
            V = __builtin_fmaf(g, V, (1.f - g) * hw);
            G *= g;
        }
    }
    gvs[seg][col] = make_float2(G, V);
    __syncthreads();

    // compose: 256 threads scan the 4 segment transforms per column
    if (t < 256) {
        float s = 0.f;
#pragma unroll
        for (int sg = 0; sg < 4; ++sg) {
            sins[sg][t] = s;
            float2 gv = gvs[sg][t];
            s = __builtin_fmaf(gv.x, s, gv.y);
        }
    }
    __syncthreads();

    // phase 2: apply with incoming carry + residual; NT stores (last use)
    float s = sins[seg][col];
    uint32_t pk[16]; float xv[16];
#pragma unroll
    for (int j = 0; j < 16; ++j) pk[j] = io[base + (size_t)j * WW];
#pragma unroll
    for (int j = 0; j < 16; ++j) xv[j] = __builtin_nontemporal_load(x + base + (size_t)j * WW);
    for (int grp = 0; grp < 4; ++grp) {
        uint32_t npk[16]; float nxv[16];
        if (grp < 3) {
            size_t nb = base + (size_t)(grp + 1) * 16 * WW;
#pragma unroll
            for (int j = 0; j < 16; ++j) npk[j] = io[nb + (size_t)j * WW];
#pragma unroll
            for (int j = 0; j < 16; ++j) nxv[j] = __builtin_nontemporal_load(x + nb + (size_t)j * WW);
        }
        size_t ob = base + (size_t)grp * 16 * WW;
#pragma unroll
        for (int j = 0; j < 16; ++j) {
            float g   = __uint_as_float(pk[j] << 16);
            float hwv = __uint_as_float(pk[j] & 0xffff0000u);
            s = __builtin_fmaf(g, s, (1.f - g) * hwv);
            __builtin_nontemporal_store(__float_as_uint(xv[j] + s), io + ob + (size_t)j * WW);
        }
#pragma unroll
        for (int j = 0; j < 16; ++j) { pk[j] = npk[j]; xv[j] = nxv[j]; }
    }
}

extern "C" void kernel_launch(void* const* d_in, const int* in_sizes, int n_in,
                              void* d_out, int out_size, void* d_ws, size_t ws_size,
                              hipStream_t stream) {
    const float* x      = (const float*)d_in[0];
    const float* gn_w   = (const float*)d_in[1];
    const float* gn_b   = (const float*)d_in[2];
    const float* gate_w = (const float*)d_in[3];
    const float* gate_b = (const float*)d_in[4];
    const float* upd_w  = (const float*)d_in[5];
    const float* upd_b  = (const float*)d_in[6];

    char* ws = (char*)d_ws;
    float2*   part  = (float2*)(ws + WS_PART_OFF);
    float2*   aff   = (float2*)(ws + WS_AFF_OFF);
    uint32_t* wfrag = (uint32_t*)(ws + WS_WFRAG_OFF);
    uint32_t* pair  = (uint32_t*)d_out;   // packed (gate,hw); K3 rewrites in place

    k_stats_partial<<<512, 256, 0, stream>>>(x, part, gate_w, upd_w, wfrag);
    k_stats_final<<<1, 512, 0, stream>>>(part, gn_w, gn_b, aff);
    k_row<<<BB * HH, 256, 0, stream>>>(x, wfrag, gate_b, upd_b, aff, pair);
    k_hscan2<<<BB * CC, 1024, 0, stream>>>(pair, x);
}